// Round 16
// baseline (404.585 us; speedup 1.0000x reference)
//
#include <hip/hip_runtime.h>
#include <hip/hip_bf16.h>
#include <stdint.h>

typedef float f32x4 __attribute__((ext_vector_type(4)));
typedef int i32x4 __attribute__((ext_vector_type(4)));

#define MROWS 8192
#define DD 1024
#define DN 4096

__device__ __forceinline__ void load_lds16(const void* g, void* l) {
  __builtin_amdgcn_global_load_lds((const __attribute__((address_space(1))) void*)g,
                                   (__attribute__((address_space(3))) void*)l, 16, 0, 0);
}

// ============================================================================
// 256x256 8-phase INT8 GEMM with A AND B register double-buffers (all
// ds_reads at phase top; nothing after the MFMA cluster). K bytes,
// K-tile=128B, NT=K>>7. Supertile bid mapping (grid 512): XCD 4x2, 8x8
// panels/XCD. vmcnt(6) odd phases. B-set pairing: pair (P,KH) phases use
// bS[pair&1], loaded 1 phase before the pair, overwritten 2 phases after
// last use. EPI 0: relu->bf16. EPI 1: + block sum -> atomicAdd(vsum).
// ============================================================================
template<int EPI>
__global__ void __launch_bounds__(512, 1)
gemm_i8_8ph(const uint8_t* __restrict__ A, const uint8_t* __restrict__ B,
            __hip_bfloat16* __restrict__ Cb, int M, int N, int K,
            float* __restrict__ vsum,
            const float* __restrict__ sA, const float* __restrict__ sB)
{
  extern __shared__ __align__(16) char smem[];
  const int tid  = threadIdx.x;
  const int lane = tid & 63;
  const int wave = tid >> 6;
  const int wm = wave >> 2;
  const int wn = wave & 3;

  // supertile: xcd in 4x2 grid, 8x8 panels per XCD (bijective for 512 blocks)
  const int xcd = (int)blockIdx.x & 7;
  const int loc = (int)blockIdx.x >> 3;   // 0..63
  const int bm = ((((xcd >> 1) << 3) + (loc >> 3)) << 8);
  const int bn = ((((xcd & 1) << 3) + (loc & 7)) << 8);

  const int NT = K >> 7;

  i32x4 acc[8][4];
  const i32x4 izero = {0, 0, 0, 0};
#pragma unroll
  for (int i = 0; i < 8; ++i)
#pragma unroll
    for (int j = 0; j < 4; ++j)
      acc[i][j] = izero;

  const int csb = (((tid & 3) ^ ((tid >> 3) & 3)) << 4);
  const uint8_t* Ag = A + (size_t)(bm + (tid >> 2)) * K + csb;
  const uint8_t* Bg = B + (size_t)(bn + (tid >> 2)) * K + csb;

  const int rl = lane & 15;
  const int kc = lane >> 4;
  const int chunk_off = ((kc ^ ((rl >> 1) & 3)) << 4);
  const int aoff = ((wm << 7) + rl) * 64 + chunk_off;
  const int boff = ((wn << 6) + rl) * 64 + chunk_off;

#define STAGE_A8(S, KH) do { \
    const int kt_ = (((S) & (NT - 1)) << 7) + ((KH) << 6); \
    char* dst_ = smem + (((((S) & 1) << 1) | (KH)) << 14) + (tid << 4); \
    load_lds16(Ag + kt_, dst_); \
    load_lds16(Ag + (size_t)128 * K + kt_, dst_ + 8192); \
  } while (0)

#define STAGE_B8(S, KH) do { \
    const int kt_ = (((S) & (NT - 1)) << 7) + ((KH) << 6); \
    char* dst_ = smem + 65536 + (((((S) & 1) << 1) | (KH)) << 14) + (tid << 4); \
    load_lds16(Bg + kt_, dst_); \
    load_lds16(Bg + (size_t)128 * K + kt_, dst_ + 8192); \
  } while (0)

  i32x4 afS[2][4];
  i32x4 bS[2][4];

#define MFMA_ROW8(MI, AF, BC) \
    acc[MI][0] = __builtin_amdgcn_mfma_i32_16x16x64_i8(AF, bS[BC][0], acc[MI][0], 0, 0, 0); \
    acc[MI][1] = __builtin_amdgcn_mfma_i32_16x16x64_i8(AF, bS[BC][1], acc[MI][1], 0, 0, 0); \
    acc[MI][2] = __builtin_amdgcn_mfma_i32_16x16x64_i8(AF, bS[BC][2], acc[MI][2], 0, 0, 0); \
    acc[MI][3] = __builtin_amdgcn_mfma_i32_16x16x64_i8(AF, bS[BC][3], acc[MI][3], 0, 0, 0);

// All reads at phase top: next-phase A frags -> afS[ASETN]; optionally the
// next pair's B frags -> bS[BSETN]. MFMA consumes afS[ACUR] x bS[BCUR].
#define PH8(PN, KHN, MHN, ASETN, DOB, BPN, BKHN, BSETN, ACUR, BCUR, MHC, STG, VM) do { \
    { const char* ab_ = smem + ((((PN) << 1) | (KHN)) << 14) + aoff + (MHN) * 4096; \
      afS[ASETN][0] = *(const i32x4*)(ab_); \
      afS[ASETN][1] = *(const i32x4*)(ab_ + 1024); \
      afS[ASETN][2] = *(const i32x4*)(ab_ + 2048); \
      afS[ASETN][3] = *(const i32x4*)(ab_ + 3072); } \
    if (DOB) { \
      const char* bb_ = smem + 65536 + ((((BPN) << 1) | (BKHN)) << 14) + boff; \
      bS[BSETN][0] = *(const i32x4*)(bb_); \
      bS[BSETN][1] = *(const i32x4*)(bb_ + 1024); \
      bS[BSETN][2] = *(const i32x4*)(bb_ + 2048); \
      bS[BSETN][3] = *(const i32x4*)(bb_ + 3072); } \
    STG; \
    if (VM) { asm volatile("s_waitcnt vmcnt(6)" ::: "memory"); } \
    asm volatile("s_barrier" ::: "memory"); \
    __builtin_amdgcn_sched_barrier(0); \
    __builtin_amdgcn_s_setprio(1); \
    MFMA_ROW8((MHC) * 4 + 0, afS[ACUR][0], BCUR) \
    MFMA_ROW8((MHC) * 4 + 1, afS[ACUR][1], BCUR) \
    MFMA_ROW8((MHC) * 4 + 2, afS[ACUR][2], BCUR) \
    MFMA_ROW8((MHC) * 4 + 3, afS[ACUR][3], BCUR) \
    __builtin_amdgcn_s_setprio(0); \
    asm volatile("s_barrier" ::: "memory"); \
  } while (0)

  STAGE_A8(0, 0); STAGE_B8(0, 0);
  STAGE_A8(0, 1); STAGE_B8(0, 1);
  STAGE_A8(1, 0); STAGE_B8(1, 0);
  asm volatile("s_waitcnt vmcnt(4)" ::: "memory");
  asm volatile("s_barrier" ::: "memory");
  {
    const char* ab_ = smem + aoff;           // slot(0,0) MH0 -> afS[1]
    afS[1][0] = *(const i32x4*)(ab_);
    afS[1][1] = *(const i32x4*)(ab_ + 1024);
    afS[1][2] = *(const i32x4*)(ab_ + 2048);
    afS[1][3] = *(const i32x4*)(ab_ + 3072);
    const char* bb_ = smem + 65536 + boff;   // pair(0,0) -> bS[0]
    bS[0][0] = *(const i32x4*)(bb_);
    bS[0][1] = *(const i32x4*)(bb_ + 1024);
    bS[0][2] = *(const i32x4*)(bb_ + 2048);
    bS[0][3] = *(const i32x4*)(bb_ + 3072);
  }

  // pair (P,KH) -> phases: (0,0):1,2 bS0 | (0,1):3,4 bS1 | (1,0):5,6 bS0 |
  // (1,1):7,8 bS1. B-top loads one phase before the pair begins.
#pragma unroll 1
  for (int t = 0; t < NT; t += 2) {
    PH8(0, 0, 1, 0,  0, 0, 0, 0,  1, 0, 0, STAGE_A8(t + 1, 1), 1); // ph1
    PH8(0, 1, 0, 1,  1, 0, 1, 1,  0, 0, 1, STAGE_B8(t + 1, 1), 0); // ph2
    PH8(0, 1, 1, 0,  0, 0, 0, 0,  1, 1, 0, STAGE_A8(t + 2, 0), 1); // ph3
    PH8(1, 0, 0, 1,  1, 1, 0, 0,  0, 1, 1, STAGE_B8(t + 2, 0), 0); // ph4
    PH8(1, 0, 1, 0,  0, 0, 0, 0,  1, 0, 0, STAGE_A8(t + 2, 1), 1); // ph5
    PH8(1, 1, 0, 1,  1, 1, 1, 1,  0, 0, 1, STAGE_B8(t + 2, 1), 0); // ph6
    PH8(1, 1, 1, 0,  0, 0, 0, 0,  1, 1, 0, STAGE_A8(t + 3, 0), 1); // ph7
    PH8(0, 0, 0, 1,  1, 0, 0, 0,  0, 1, 1, STAGE_B8(t + 3, 0), 0); // ph8
  }

  const int r0 = bm + (wm << 7) + (kc << 2);
  const int c0 = bn + (wn << 6) + rl;
  float lsum = 0.f;
#pragma unroll
  for (int mi = 0; mi < 8; ++mi) {
#pragma unroll
    for (int nf = 0; nf < 4; ++nf) {
#pragma unroll
      for (int q = 0; q < 4; ++q) {
        const int r = r0 + (mi << 4) + q;
        const int c = c0 + (nf << 4);
        float v = (float)acc[mi][nf][q] * sA[r] * sB[c];
        v = fmaxf(v, 0.f);
        Cb[(size_t)r * N + c] = __float2bfloat16(v);
        if constexpr (EPI == 1) lsum += v;
      }
    }
  }
  if constexpr (EPI == 1) {
#pragma unroll
    for (int off = 32; off > 0; off >>= 1)
      lsum += __shfl_down(lsum, off);
    if (lane == 0) atomicAdd(vsum, lsum);
  }

#undef STAGE_A8
#undef STAGE_B8
#undef MFMA_ROW8
#undef PH8
}

// ============================================================================
// 128x128 2-barrier INT8 GEMM (verified) + XCD swizzle — pred:
// pred = (spq @ wuq^T) * sA[r] * sB[c] -> bf16 (no relu).
// ============================================================================
__global__ void __launch_bounds__(256)
gemm_i8_128(const uint8_t* __restrict__ A, const uint8_t* __restrict__ B,
            __hip_bfloat16* __restrict__ Cb, int M, int N, int K,
            const float* __restrict__ sA, const float* __restrict__ sB)
{
  __shared__ __align__(16) char smem[32768];
  const int tid  = threadIdx.x;
  const int lane = tid & 63;
  const int wave = tid >> 6;

  const int nwg = gridDim.x;
  const int bid = ((int)blockIdx.x % 8) * (nwg >> 3) + ((int)blockIdx.x >> 3);

  const int nbn = N >> 7;
  const int bm = (bid / nbn) << 7;
  const int bn = (bid % nbn) << 7;

  const int wm = (wave >> 1) << 6;
  const int wn = (wave & 1) << 6;

  i32x4 acc[4][4];
  const i32x4 izero = {0, 0, 0, 0};
#pragma unroll
  for (int i = 0; i < 4; ++i)
#pragma unroll
    for (int j = 0; j < 4; ++j)
      acc[i][j] = izero;

  const int srow = tid >> 3;
  const int schk = (tid & 7) ^ (srow & 7);
  const uint8_t* Ag = A + (size_t)(bm + srow) * K + (schk << 4);
  const uint8_t* Bg = B + (size_t)(bn + srow) * K + (schk << 4);
  char* ldsA = smem + (wave << 10);
  char* ldsB = smem + 16384 + (wave << 10);

  const int aoff0 = (wm + (lane & 15)) << 7;
  const int boff0 = 16384 + ((wn + (lane & 15)) << 7);
  const int kc = lane >> 4;
  const int sw = lane & 7;

  for (int k0 = 0; k0 < K; k0 += 128) {
#pragma unroll
    for (int i = 0; i < 4; ++i)
      load_lds16(Ag + (size_t)(i << 5) * K + k0, ldsA + (i << 12));
#pragma unroll
    for (int i = 0; i < 4; ++i)
      load_lds16(Bg + (size_t)(i << 5) * K + k0, ldsB + (i << 12));
    __syncthreads();
#pragma unroll
    for (int ks = 0; ks < 2; ++ks) {
      const int cb = ((kc + (ks << 2)) ^ sw) << 4;
      i32x4 af[4], bfr[4];
#pragma unroll
      for (int i = 0; i < 4; ++i)
        af[i] = *reinterpret_cast<const i32x4*>(smem + aoff0 + (i << 11) + cb);
#pragma unroll
      for (int j = 0; j < 4; ++j)
        bfr[j] = *reinterpret_cast<const i32x4*>(smem + boff0 + (j << 11) + cb);
#pragma unroll
      for (int i = 0; i < 4; ++i)
#pragma unroll
        for (int j = 0; j < 4; ++j)
          acc[i][j] = __builtin_amdgcn_mfma_i32_16x16x64_i8(af[i], bfr[j], acc[i][j], 0, 0, 0);
    }
    __syncthreads();
  }

  const int r0 = bm + wm + ((lane >> 4) << 2);
  const int c0 = bn + wn + (lane & 15);
#pragma unroll
  for (int i = 0; i < 4; ++i)
#pragma unroll
    for (int j = 0; j < 4; ++j)
#pragma unroll
      for (int q = 0; q < 4; ++q) {
        const int r = r0 + (i << 4) + q;
        const int c = c0 + (j << 4);
        Cb[(size_t)r * N + c] =
            __float2bfloat16((float)acc[i][j][q] * sA[r] * sB[c]);
      }
}

// ============================================================================
// 128x128 2-barrier INT8 gate GEMM + fused final epilogue (verified):
// out = x + sigmoid(deq(xq@wgq^T) + bgate) * pred(bf16)   (f32 out)
// ============================================================================
__global__ void __launch_bounds__(256)
gemm_gate_i8(const uint8_t* __restrict__ A, const uint8_t* __restrict__ B,
             float* __restrict__ Cf, int M, int N, int K,
             const float* __restrict__ sA, const float* __restrict__ sB,
             const float* __restrict__ Xf, const __hip_bfloat16* __restrict__ PredBf,
             const float* __restrict__ Bgate)
{
  __shared__ __align__(16) char smem[32768];
  const int tid  = threadIdx.x;
  const int lane = tid & 63;
  const int wave = tid >> 6;

  const int nwg = gridDim.x;
  const int bid = ((int)blockIdx.x % 8) * (nwg >> 3) + ((int)blockIdx.x >> 3);

  const int nbn = N >> 7;
  const int bm = (bid / nbn) << 7;
  const int bn = (bid % nbn) << 7;

  const int wm = (wave >> 1) << 6;
  const int wn = (wave & 1) << 6;

  i32x4 acc[4][4];
  const i32x4 izero = {0, 0, 0, 0};
#pragma unroll
  for (int i = 0; i < 4; ++i)
#pragma unroll
    for (int j = 0; j < 4; ++j) acc[i][j] = izero;

  const int srow = tid >> 3;
  const int schk = (tid & 7) ^ (srow & 7);
  const uint8_t* Ag = A + (size_t)(bm + srow) * K + (schk << 4);
  const uint8_t* Bg = B + (size_t)(bn + srow) * K + (schk << 4);
  char* ldsA = smem + (wave << 10);
  char* ldsB = smem + 16384 + (wave << 10);

  const int aoff0 = (wm + (lane & 15)) << 7;
  const int boff0 = 16384 + ((wn + (lane & 15)) << 7);
  const int kc = lane >> 4;
  const int sw = lane & 7;

  for (int k0 = 0; k0 < K; k0 += 128) {
#pragma unroll
    for (int i = 0; i < 4; ++i)
      load_lds16(Ag + (size_t)(i << 5) * K + k0, ldsA + (i << 12));
#pragma unroll
    for (int i = 0; i < 4; ++i)
      load_lds16(Bg + (size_t)(i << 5) * K + k0, ldsB + (i << 12));
    __syncthreads();
#pragma unroll
    for (int ks = 0; ks < 2; ++ks) {
      const int cb = ((kc + (ks << 2)) ^ sw) << 4;
      i32x4 af[4], bfr[4];
#pragma unroll
      for (int i = 0; i < 4; ++i)
        af[i] = *reinterpret_cast<const i32x4*>(smem + aoff0 + (i << 11) + cb);
#pragma unroll
      for (int j = 0; j < 4; ++j)
        bfr[j] = *reinterpret_cast<const i32x4*>(smem + boff0 + (j << 11) + cb);
#pragma unroll
      for (int i = 0; i < 4; ++i)
#pragma unroll
        for (int j = 0; j < 4; ++j)
          acc[i][j] = __builtin_amdgcn_mfma_i32_16x16x64_i8(af[i], bfr[j], acc[i][j], 0, 0, 0);
    }
    __syncthreads();
  }

  const int r0 = bm + wm + ((lane >> 4) << 2);
  const int c0 = bn + wn + (lane & 15);
#pragma unroll
  for (int i = 0; i < 4; ++i)
#pragma unroll
    for (int j = 0; j < 4; ++j)
#pragma unroll
      for (int q = 0; q < 4; ++q) {
        const int r = r0 + (i << 4) + q;
        const int c = c0 + (j << 4);
        const size_t idx = (size_t)r * N + c;
        const float vg = (float)acc[i][j][q] * sA[r] * sB[c] + Bgate[c];
        const float g = 1.f / (1.f + __expf(-vg));
        Cf[idx] = Xf[idx] + g * __bfloat162float(PredBf[idx]);
      }
}

// ============================================================================
// kwta, wave-per-row (verified). Exact threshold via 16-step binary search on
// u16 bf16 keys (nonneg). Emits INT8 normalized row + scale.
// MODE 0: always write.  MODE 1: only when *vsumPtr >= EPS (else keep old).
// ============================================================================
template<int MODE>
__global__ void __launch_bounds__(256)
kwta_wave(const __hip_bfloat16* __restrict__ H, uint8_t* __restrict__ OUTQ,
          float* __restrict__ sA, const float* __restrict__ vsumPtr,
          const int* __restrict__ kptr)
{
  const int tid  = threadIdx.x;
  const int lane = tid & 63;
  const int w    = tid >> 6;
  const int row  = ((int)blockIdx.x << 2) + w;

  if constexpr (MODE == 1) {
    if (!(*vsumPtr >= 1e-10f)) return;
  }

  const uint4* h8 = (const uint4*)(H + (size_t)row * 4096);
  uint4 d[8];
#pragma unroll
  for (int i = 0; i < 8; ++i) d[i] = h8[(i << 6) + lane];

  const unsigned k = (unsigned)(*kptr);

  unsigned kmax = 0;
#pragma unroll
  for (int i = 0; i < 8; ++i) {
    const unsigned* p = (const unsigned*)&d[i];
#pragma unroll
    for (int c4 = 0; c4 < 4; ++c4) {
      kmax = max(kmax, p[c4] & 0xffffu);
      kmax = max(kmax, p[c4] >> 16);
    }
  }
#pragma unroll
  for (int off = 32; off > 0; off >>= 1) kmax = max(kmax, __shfl_xor(kmax, off));

  unsigned lo = 0, hi = 65536;
#pragma unroll 1
  for (int it = 0; it < 16; ++it) {
    const unsigned mid = (lo + hi) >> 1;
    unsigned c = 0;
#pragma unroll
    for (int i = 0; i < 8; ++i) {
      const unsigned* p = (const unsigned*)&d[i];
#pragma unroll
      for (int c4 = 0; c4 < 4; ++c4) {
        c += ((p[c4] & 0xffffu) >= mid) ? 1u : 0u;
        c += ((p[c4] >> 16) >= mid) ? 1u : 0u;
      }
    }
#pragma unroll
    for (int off = 32; off > 0; off >>= 1) c += __shfl_xor(c, off);
    if (c >= k) lo = mid; else hi = mid;
  }
  const unsigned threshKey = lo;

  float ss = 0.f;
#pragma unroll
  for (int i = 0; i < 8; ++i) {
    const unsigned* p = (const unsigned*)&d[i];
#pragma unroll
    for (int c4 = 0; c4 < 4; ++c4) {
#pragma unroll
      for (int hh = 0; hh < 2; ++hh) {
        const unsigned key = hh ? (p[c4] >> 16) : (p[c4] & 0xffffu);
        if (key >= threshKey) {
          const float v = __uint_as_float(key << 16);
          ss = fmaf(v, v, ss);
        }
      }
    }
  }
#pragma unroll
  for (int off = 32; off > 0; off >>= 1) ss += __shfl_xor(ss, off);
  const float inv = 1.f / fmaxf(sqrtf(ss), 1e-10f);

  const float vmaxf = __uint_as_float(kmax << 16);
  const float r127 = (kmax > 0) ? 127.f / vmaxf : 0.f;

  if (lane == 0) sA[row] = vmaxf * inv * (1.f / 127.f);

  uint2* o2 = (uint2*)(OUTQ + (size_t)row * 4096);
#pragma unroll
  for (int i = 0; i < 8; ++i) {
    const unsigned* p = (const unsigned*)&d[i];
    unsigned b[8];
#pragma unroll
    for (int c4 = 0; c4 < 4; ++c4) {
#pragma unroll
      for (int hh = 0; hh < 2; ++hh) {
        const unsigned key = hh ? (p[c4] >> 16) : (p[c4] & 0xffffu);
        unsigned q = 0;
        if (key >= threshKey && key > 0) {
          const float v = __uint_as_float(key << 16);
          q = (unsigned)__float2int_rn(v * r127) & 0xffu;
        }
        b[c4 * 2 + hh] = q;
      }
    }
    uint2 o;
    o.x = b[0] | (b[1] << 8) | (b[2] << 16) | (b[3] << 24);
    o.y = b[4] | (b[5] << 8) | (b[6] << 16) | (b[7] << 24);
    o2[(i << 6) + lane] = o;
  }
}

// ============================================================================
// Merged per-row quantization, one launch; also zero-inits vsum (block 0).
// ============================================================================
__global__ void __launch_bounds__(256)
quant_all(const float* __restrict__ X,  const float* __restrict__ Wd,
          const float* __restrict__ Wg, const float* __restrict__ Wc,
          const float* __restrict__ Wu,
          uint8_t* __restrict__ xq,  uint8_t* __restrict__ wdq,
          uint8_t* __restrict__ wgq, uint8_t* __restrict__ wcq,
          uint8_t* __restrict__ wuq,
          float* __restrict__ sx,  float* __restrict__ swd,
          float* __restrict__ swg, float* __restrict__ swc,
          float* __restrict__ swu, float* __restrict__ vsum)
{
  if (blockIdx.x == 0 && threadIdx.x == 0) *vsum = 0.f;

  const int wgl = ((int)blockIdx.x << 2) + (threadIdx.x >> 6);
  const int lane = threadIdx.x & 63;

  const float* W; uint8_t* q; float* s; int row; bool big;
  if      (wgl < 8192)  { W = X;  q = xq;  s = sx;  row = wgl;         big = false; }
  else if (wgl < 12288) { W = Wd; q = wdq; s = swd; row = wgl - 8192;  big = false; }
  else if (wgl < 13312) { W = Wg; q = wgq; s = swg; row = wgl - 12288; big = false; }
  else if (wgl < 17408) { W = Wc; q = wcq; s = swc; row = wgl - 13312; big = true; }
  else                  { W = Wu; q = wuq; s = swu; row = wgl - 17408; big = true; }

  if (!big) {
    const float4* src = (const float4*)(W + (size_t)row * 1024);
    float4 v[4];
    float am = 0.f;
#pragma unroll
    for (int i = 0; i < 4; ++i) {
      v[i] = src[(i << 6) + lane];
      am = fmaxf(am, fmaxf(fmaxf(fabsf(v[i].x), fabsf(v[i].y)),
                           fmaxf(fabsf(v[i].z), fabsf(v[i].w))));
    }
#pragma unroll
    for (int off = 32; off > 0; off >>= 1) am = fmaxf(am, __shfl_xor(am, off));
    const float rinv = (am > 0.f) ? 127.f / am : 0.f;
    uint4 o;
    unsigned* ob = (unsigned*)&o;
#pragma unroll
    for (int i = 0; i < 4; ++i) {
      const unsigned b0 = (unsigned)__float2int_rn(v[i].x * rinv) & 0xffu;
      const unsigned b1 = (unsigned)__float2int_rn(v[i].y * rinv) & 0xffu;
      const unsigned b2 = (unsigned)__float2int_rn(v[i].z * rinv) & 0xffu;
      const unsigned b3 = (unsigned)__float2int_rn(v[i].w * rinv) & 0xffu;
      ob[i] = b0 | (b1 << 8) | (b2 << 16) | (b3 << 24);
    }
    ((uint4*)(q + (size_t)row * 1024))[lane] = o;
    if (lane == 0) s[row] = am * (1.f / 127.f);
  } else {
    const float4* src = (const float4*)(W + (size_t)row * 4096);
    float4 v[16];
    float am = 0.f;
#pragma unroll
    for (int i = 0; i < 16; ++i) {
      v[i] = src[(i << 6) + lane];
      am = fmaxf(am, fmaxf(fmaxf(fabsf(v[i].x), fabsf(v[i].y)),
                           fmaxf(fabsf(v[i].z), fabsf(v[i].w))));
    }
#pragma unroll
    for (int off = 32; off > 0; off >>= 1) am = fmaxf(am, __shfl_xor(am, off));
    const float rinv = (am > 0.f) ? 127.f / am : 0.f;
    unsigned* qo = (unsigned*)(q + (size_t)row * 4096);
#pragma unroll
    for (int i = 0; i < 16; ++i) {
      const unsigned b0 = (unsigned)__float2int_rn(v[i].x * rinv) & 0xffu;
      const unsigned b1 = (unsigned)__float2int_rn(v[i].y * rinv) & 0xffu;
      const unsigned b2 = (unsigned)__float2int_rn(v[i].z * rinv) & 0xffu;
      const unsigned b3 = (unsigned)__float2int_rn(v[i].w * rinv) & 0xffu;
      qo[(i << 6) + lane] = b0 | (b1 << 8) | (b2 << 16) | (b3 << 24);
    }
    if (lane == 0) s[row] = am * (1.f / 127.f);
  }
}

__global__ void diag_kernel(float* out, float mb)
{
  if (threadIdx.x == 0 && blockIdx.x == 0) out[0] = -mb;
}

extern "C" void kernel_launch(void* const* d_in, const int* in_sizes, int n_in,
                              void* d_out, int out_size, void* d_ws, size_t ws_size,
                              hipStream_t stream)
{
  const float* x     = (const float*)d_in[0]; // (8192,1024)
  const float* Wdown = (const float*)d_in[1]; // (4096,1024)
  const float* Wup   = (const float*)d_in[2]; // (1024,4096)
  const float* Wgate = (const float*)d_in[3]; // (1024,1024)
  const float* bgate = (const float*)d_in[4]; // (1024,)
  const float* Wca3  = (const float*)d_in[5]; // (4096,4096)
  const int*   kptr  = (const int*)d_in[6];

  const size_t OFF_XQ   = 0;         //  8 MB i8 x
  const size_t OFF_WDQ  = 8388608;   //  4 MB i8 W_down
  const size_t OFF_WGQ  = 12582912;  //  1 MB i8 W_gate
  const size_t OFF_WCQ  = 13631488;  // 16 MB i8 W_ca3
  const size_t OFF_WUQ  = 30408704;  //  4 MB i8 W_up
  const size_t OFF_SX   = 34603008;  // 32 KB
  const size_t OFF_SWD  = 34635776;  // 16 KB
  const size_t OFF_SWG  = 34652160;  //  4 KB
  const size_t OFF_SWC  = 34656256;  // 16 KB
  const size_t OFF_SWU  = 34672640;  //  4 KB
  const size_t OFF_SA   = 34676736;  // 32 KB
  const size_t OFF_VSUM = 34709504;  //  4 KB pad
  const size_t OFF_SPQ  = 34713600;  // 32 MB i8 sparse/successor
  const size_t OFF_H    = 68268032;  // 64 MB bf16 h1/h2; pred (16 MB bf16) aliases
  const size_t NEED     = 135376896;

  if (ws_size < NEED) {
    diag_kernel<<<1, 64, 0, stream>>>((float*)d_out, (float)(ws_size >> 20));
    return;
  }

  char* ws = (char*)d_ws;
  uint8_t*        xq   = (uint8_t*)       (ws + OFF_XQ);
  uint8_t*        wdq  = (uint8_t*)       (ws + OFF_WDQ);
  uint8_t*        wgq  = (uint8_t*)       (ws + OFF_WGQ);
  uint8_t*        wcq  = (uint8_t*)       (ws + OFF_WCQ);
  uint8_t*        wuq  = (uint8_t*)       (ws + OFF_WUQ);
  float*          sx   = (float*)         (ws + OFF_SX);
  float*          swd  = (float*)         (ws + OFF_SWD);
  float*          swg  = (float*)         (ws + OFF_SWG);
  float*          swc  = (float*)         (ws + OFF_SWC);
  float*          swu  = (float*)         (ws + OFF_SWU);
  float*          sA   = (float*)         (ws + OFF_SA);
  float*          vsum = (float*)         (ws + OFF_VSUM);
  uint8_t*        spq  = (uint8_t*)       (ws + OFF_SPQ);
  __hip_bfloat16* h    = (__hip_bfloat16*)(ws + OFF_H);
  __hip_bfloat16* pred = (__hip_bfloat16*)(ws + OFF_H);   // aliases h (dead by then)

  // quantize all inputs/weights to i8 with per-row scales; zero vsum
  quant_all<<<4608, 256, 0, stream>>>(x, Wdown, Wgate, Wca3, Wup,
                                      xq, wdq, wgq, wcq, wuq,
                                      sx, swd, swg, swc, swu, vsum);

  // h1 = relu(sx*swd * (xq @ wdq^T)) -> bf16   [i8 8-phase 256^2, supertile]
  gemm_i8_8ph<0><<<(MROWS >> 8) * (DN >> 8), 512, 131072, stream>>>(
      xq, wdq, h, MROWS, DN, DD, nullptr, sx, swd);
  // sparse = kwta(h1)/norm -> i8 + scale
  kwta_wave<0><<<MROWS / 4, 256, 0, stream>>>(h, spq, sA, nullptr, kptr);
  // h2 = relu(sA*swc * (spq @ wcq^T)) -> bf16, sum -> vsum   [i8 8-phase]
  gemm_i8_8ph<1><<<(MROWS >> 8) * (DN >> 8), 512, 131072, stream>>>(
      spq, wcq, h, MROWS, DN, DN, vsum, sA, swc);
  // successor = valid ? kwta(h2)/norm : sparse (i8 + scale, in-place)
  kwta_wave<1><<<MROWS / 4, 256, 0, stream>>>(h, spq, sA, vsum, kptr);
  // pred = (spq @ wuq^T) deq -> bf16   [i8 128^2 + swizzle, grid 512]
  gemm_i8_128<<<(MROWS >> 7) * (DD >> 7), 256, 0, stream>>>(
      spq, wuq, pred, MROWS, DD, DN, sA, swu);
  // out = x + sigmoid(deq(xq @ wgq^T) + bgate) * pred   [i8 128^2]
  gemm_gate_i8<<<(MROWS >> 7) * (DD >> 7), 256, 0, stream>>>(
      xq, wgq, (float*)d_out, MROWS, DD, DD, sx, swg, x, pred, bgate);
}

// Round 17
// 397.900 us; speedup vs baseline: 1.0168x; 1.0168x over previous
//
#include <hip/hip_runtime.h>
#include <hip/hip_bf16.h>
#include <stdint.h>

typedef float f32x4 __attribute__((ext_vector_type(4)));
typedef int i32x4 __attribute__((ext_vector_type(4)));

#define MROWS 8192
#define DD 1024
#define DN 4096

__device__ __forceinline__ void load_lds16(const void* g, void* l) {
  __builtin_amdgcn_global_load_lds((const __attribute__((address_space(1))) void*)g,
                                   (__attribute__((address_space(3))) void*)l, 16, 0, 0);
}

// ============================================================================
// 256x256 8-phase INT8 GEMM (verified schedule; pipelined frag reads,
// vmcnt(6) odd phases). K bytes, K-tile=128B, NT=K>>7.
// SUPERTILE bid mapping (hardcoded for grid 512, M=8192, N=4096): XCDs tiled
// 4x2 over the 32x16 panel grid; each XCD owns an 8x8 panel chunk.
// EPI 0: h = relu(deq) -> bf16.   EPI 1: + block sum -> atomicAdd(vsum).
// ============================================================================
template<int EPI>
__global__ void __launch_bounds__(512, 1)
gemm_i8_8ph(const uint8_t* __restrict__ A, const uint8_t* __restrict__ B,
            __hip_bfloat16* __restrict__ Cb, int M, int N, int K,
            float* __restrict__ vsum,
            const float* __restrict__ sA, const float* __restrict__ sB)
{
  extern __shared__ __align__(16) char smem[];
  const int tid  = threadIdx.x;
  const int lane = tid & 63;
  const int wave = tid >> 6;
  const int wm = wave >> 2;
  const int wn = wave & 3;

  // supertile: xcd in 4x2 grid, 8x8 panels per XCD (bijective for 512 blocks)
  const int xcd = (int)blockIdx.x & 7;
  const int loc = (int)blockIdx.x >> 3;   // 0..63
  const int bm = ((((xcd >> 1) << 3) + (loc >> 3)) << 8);
  const int bn = ((((xcd & 1) << 3) + (loc & 7)) << 8);

  const int NT = K >> 7;

  i32x4 acc[8][4];
  const i32x4 izero = {0, 0, 0, 0};
#pragma unroll
  for (int i = 0; i < 8; ++i)
#pragma unroll
    for (int j = 0; j < 4; ++j)
      acc[i][j] = izero;

  const int csb = (((tid & 3) ^ ((tid >> 3) & 3)) << 4);
  const uint8_t* Ag = A + (size_t)(bm + (tid >> 2)) * K + csb;
  const uint8_t* Bg = B + (size_t)(bn + (tid >> 2)) * K + csb;

  const int rl = lane & 15;
  const int kc = lane >> 4;
  const int chunk_off = ((kc ^ ((rl >> 1) & 3)) << 4);
  const int aoff = ((wm << 7) + rl) * 64 + chunk_off;
  const int boff = ((wn << 6) + rl) * 64 + chunk_off;

#define STAGE_A8(S, KH) do { \
    const int kt_ = (((S) & (NT - 1)) << 7) + ((KH) << 6); \
    char* dst_ = smem + (((((S) & 1) << 1) | (KH)) << 14) + (tid << 4); \
    load_lds16(Ag + kt_, dst_); \
    load_lds16(Ag + (size_t)128 * K + kt_, dst_ + 8192); \
  } while (0)

#define STAGE_B8(S, KH) do { \
    const int kt_ = (((S) & (NT - 1)) << 7) + ((KH) << 6); \
    char* dst_ = smem + 65536 + (((((S) & 1) << 1) | (KH)) << 14) + (tid << 4); \
    load_lds16(Bg + kt_, dst_); \
    load_lds16(Bg + (size_t)128 * K + kt_, dst_ + 8192); \
  } while (0)

  i32x4 afS[2][4];
  i32x4 b0, b1, b2, b3;

#define MFMA_ROW8(MI, AF) \
    acc[MI][0] = __builtin_amdgcn_mfma_i32_16x16x64_i8(AF, b0, acc[MI][0], 0, 0, 0); \
    acc[MI][1] = __builtin_amdgcn_mfma_i32_16x16x64_i8(AF, b1, acc[MI][1], 0, 0, 0); \
    acc[MI][2] = __builtin_amdgcn_mfma_i32_16x16x64_i8(AF, b2, acc[MI][2], 0, 0, 0); \
    acc[MI][3] = __builtin_amdgcn_mfma_i32_16x16x64_i8(AF, b3, acc[MI][3], 0, 0, 0);

#define PH8(PN, KHN, MHN, ASETN, ACUR, MHC, DOBP, BP, BKH, STG, VM) do { \
    { const char* ab_ = smem + ((((PN) << 1) | (KHN)) << 14) + aoff + (MHN) * 4096; \
      afS[ASETN][0] = *(const i32x4*)(ab_); \
      afS[ASETN][1] = *(const i32x4*)(ab_ + 1024); \
      afS[ASETN][2] = *(const i32x4*)(ab_ + 2048); \
      afS[ASETN][3] = *(const i32x4*)(ab_ + 3072); } \
    STG; \
    if (VM) { asm volatile("s_waitcnt vmcnt(6)" ::: "memory"); } \
    asm volatile("s_barrier" ::: "memory"); \
    __builtin_amdgcn_sched_barrier(0); \
    __builtin_amdgcn_s_setprio(1); \
    MFMA_ROW8((MHC) * 4 + 0, afS[ACUR][0]) \
    MFMA_ROW8((MHC) * 4 + 1, afS[ACUR][1]) \
    MFMA_ROW8((MHC) * 4 + 2, afS[ACUR][2]) \
    MFMA_ROW8((MHC) * 4 + 3, afS[ACUR][3]) \
    __builtin_amdgcn_s_setprio(0); \
    if (DOBP) { \
      const char* bb_ = smem + 65536 + ((((BP) << 1) | (BKH)) << 14) + boff; \
      b0 = *(const i32x4*)(bb_); b1 = *(const i32x4*)(bb_ + 1024); \
      b2 = *(const i32x4*)(bb_ + 2048); b3 = *(const i32x4*)(bb_ + 3072); } \
    asm volatile("s_barrier" ::: "memory"); \
  } while (0)

  STAGE_A8(0, 0); STAGE_B8(0, 0);
  STAGE_A8(0, 1); STAGE_B8(0, 1);
  STAGE_A8(1, 0); STAGE_B8(1, 0);
  asm volatile("s_waitcnt vmcnt(4)" ::: "memory");
  asm volatile("s_barrier" ::: "memory");
  {
    const char* ab_ = smem + aoff;
    afS[1][0] = *(const i32x4*)(ab_);
    afS[1][1] = *(const i32x4*)(ab_ + 1024);
    afS[1][2] = *(const i32x4*)(ab_ + 2048);
    afS[1][3] = *(const i32x4*)(ab_ + 3072);
    const char* bb_ = smem + 65536 + boff;
    b0 = *(const i32x4*)(bb_); b1 = *(const i32x4*)(bb_ + 1024);
    b2 = *(const i32x4*)(bb_ + 2048); b3 = *(const i32x4*)(bb_ + 3072);
  }

#pragma unroll 1
  for (int t = 0; t < NT; t += 2) {
    PH8(0, 0, 1, 0, 1, 0, 0, 0, 0, STAGE_A8(t + 1, 1), 1);
    PH8(0, 1, 0, 1, 0, 1, 1, 0, 1, STAGE_B8(t + 1, 1), 0);
    PH8(0, 1, 1, 0, 1, 0, 0, 0, 0, STAGE_A8(t + 2, 0), 1);
    PH8(1, 0, 0, 1, 0, 1, 1, 1, 0, STAGE_B8(t + 2, 0), 0);
    PH8(1, 0, 1, 0, 1, 0, 0, 0, 0, STAGE_A8(t + 2, 1), 1);
    PH8(1, 1, 0, 1, 0, 1, 1, 1, 1, STAGE_B8(t + 2, 1), 0);
    PH8(1, 1, 1, 0, 1, 0, 0, 0, 0, STAGE_A8(t + 3, 0), 1);
    PH8(0, 0, 0, 1, 0, 1, 1, 0, 0, STAGE_B8(t + 3, 0), 0);
  }

  const int r0 = bm + (wm << 7) + (kc << 2);
  const int c0 = bn + (wn << 6) + rl;
  float lsum = 0.f;
#pragma unroll
  for (int mi = 0; mi < 8; ++mi) {
#pragma unroll
    for (int nf = 0; nf < 4; ++nf) {
#pragma unroll
      for (int q = 0; q < 4; ++q) {
        const int r = r0 + (mi << 4) + q;
        const int c = c0 + (nf << 4);
        float v = (float)acc[mi][nf][q] * sA[r] * sB[c];
        v = fmaxf(v, 0.f);
        Cb[(size_t)r * N + c] = __float2bfloat16(v);
        if constexpr (EPI == 1) lsum += v;
      }
    }
  }
  if constexpr (EPI == 1) {
#pragma unroll
    for (int off = 32; off > 0; off >>= 1)
      lsum += __shfl_down(lsum, off);
    if (lane == 0) atomicAdd(vsum, lsum);
  }

#undef STAGE_A8
#undef STAGE_B8
#undef MFMA_ROW8
#undef PH8
}

// ============================================================================
// 128x128 2-barrier INT8 GEMM (verified) + XCD swizzle — pred:
// pred = (spq @ wuq^T) * sA[r] * sB[c] -> bf16 (no relu).
// ============================================================================
__global__ void __launch_bounds__(256)
gemm_i8_128(const uint8_t* __restrict__ A, const uint8_t* __restrict__ B,
            __hip_bfloat16* __restrict__ Cb, int M, int N, int K,
            const float* __restrict__ sA, const float* __restrict__ sB)
{
  __shared__ __align__(16) char smem[32768];
  const int tid  = threadIdx.x;
  const int lane = tid & 63;
  const int wave = tid >> 6;

  const int nwg = gridDim.x;
  const int bid = ((int)blockIdx.x % 8) * (nwg >> 3) + ((int)blockIdx.x >> 3);

  const int nbn = N >> 7;
  const int bm = (bid / nbn) << 7;
  const int bn = (bid % nbn) << 7;

  const int wm = (wave >> 1) << 6;
  const int wn = (wave & 1) << 6;

  i32x4 acc[4][4];
  const i32x4 izero = {0, 0, 0, 0};
#pragma unroll
  for (int i = 0; i < 4; ++i)
#pragma unroll
    for (int j = 0; j < 4; ++j)
      acc[i][j] = izero;

  const int srow = tid >> 3;
  const int schk = (tid & 7) ^ (srow & 7);
  const uint8_t* Ag = A + (size_t)(bm + srow) * K + (schk << 4);
  const uint8_t* Bg = B + (size_t)(bn + srow) * K + (schk << 4);
  char* ldsA = smem + (wave << 10);
  char* ldsB = smem + 16384 + (wave << 10);

  const int aoff0 = (wm + (lane & 15)) << 7;
  const int boff0 = 16384 + ((wn + (lane & 15)) << 7);
  const int kc = lane >> 4;
  const int sw = lane & 7;

  for (int k0 = 0; k0 < K; k0 += 128) {
#pragma unroll
    for (int i = 0; i < 4; ++i)
      load_lds16(Ag + (size_t)(i << 5) * K + k0, ldsA + (i << 12));
#pragma unroll
    for (int i = 0; i < 4; ++i)
      load_lds16(Bg + (size_t)(i << 5) * K + k0, ldsB + (i << 12));
    __syncthreads();
#pragma unroll
    for (int ks = 0; ks < 2; ++ks) {
      const int cb = ((kc + (ks << 2)) ^ sw) << 4;
      i32x4 af[4], bfr[4];
#pragma unroll
      for (int i = 0; i < 4; ++i)
        af[i] = *reinterpret_cast<const i32x4*>(smem + aoff0 + (i << 11) + cb);
#pragma unroll
      for (int j = 0; j < 4; ++j)
        bfr[j] = *reinterpret_cast<const i32x4*>(smem + boff0 + (j << 11) + cb);
#pragma unroll
      for (int i = 0; i < 4; ++i)
#pragma unroll
        for (int j = 0; j < 4; ++j)
          acc[i][j] = __builtin_amdgcn_mfma_i32_16x16x64_i8(af[i], bfr[j], acc[i][j], 0, 0, 0);
    }
    __syncthreads();
  }

  const int r0 = bm + wm + ((lane >> 4) << 2);
  const int c0 = bn + wn + (lane & 15);
#pragma unroll
  for (int i = 0; i < 4; ++i)
#pragma unroll
    for (int j = 0; j < 4; ++j)
#pragma unroll
      for (int q = 0; q < 4; ++q) {
        const int r = r0 + (i << 4) + q;
        const int c = c0 + (j << 4);
        Cb[(size_t)r * N + c] =
            __float2bfloat16((float)acc[i][j][q] * sA[r] * sB[c]);
      }
}

// ============================================================================
// 128x128 2-barrier INT8 gate GEMM + fused final epilogue:
// out = x + sigmoid(deq(xq@wgq^T) + bgate) * pred(bf16)   (f32 out)
// ============================================================================
__global__ void __launch_bounds__(256)
gemm_gate_i8(const uint8_t* __restrict__ A, const uint8_t* __restrict__ B,
             float* __restrict__ Cf, int M, int N, int K,
             const float* __restrict__ sA, const float* __restrict__ sB,
             const float* __restrict__ Xf, const __hip_bfloat16* __restrict__ PredBf,
             const float* __restrict__ Bgate)
{
  __shared__ __align__(16) char smem[32768];
  const int tid  = threadIdx.x;
  const int lane = tid & 63;
  const int wave = tid >> 6;

  const int nwg = gridDim.x;
  const int bid = ((int)blockIdx.x % 8) * (nwg >> 3) + ((int)blockIdx.x >> 3);

  const int nbn = N >> 7;
  const int bm = (bid / nbn) << 7;
  const int bn = (bid % nbn) << 7;

  const int wm = (wave >> 1) << 6;
  const int wn = (wave & 1) << 6;

  i32x4 acc[4][4];
  const i32x4 izero = {0, 0, 0, 0};
#pragma unroll
  for (int i = 0; i < 4; ++i)
#pragma unroll
    for (int j = 0; j < 4; ++j) acc[i][j] = izero;

  const int srow = tid >> 3;
  const int schk = (tid & 7) ^ (srow & 7);
  const uint8_t* Ag = A + (size_t)(bm + srow) * K + (schk << 4);
  const uint8_t* Bg = B + (size_t)(bn + srow) * K + (schk << 4);
  char* ldsA = smem + (wave << 10);
  char* ldsB = smem + 16384 + (wave << 10);

  const int aoff0 = (wm + (lane & 15)) << 7;
  const int boff0 = 16384 + ((wn + (lane & 15)) << 7);
  const int kc = lane >> 4;
  const int sw = lane & 7;

  for (int k0 = 0; k0 < K; k0 += 128) {
#pragma unroll
    for (int i = 0; i < 4; ++i)
      load_lds16(Ag + (size_t)(i << 5) * K + k0, ldsA + (i << 12));
#pragma unroll
    for (int i = 0; i < 4; ++i)
      load_lds16(Bg + (size_t)(i << 5) * K + k0, ldsB + (i << 12));
    __syncthreads();
#pragma unroll
    for (int ks = 0; ks < 2; ++ks) {
      const int cb = ((kc + (ks << 2)) ^ sw) << 4;
      i32x4 af[4], bfr[4];
#pragma unroll
      for (int i = 0; i < 4; ++i)
        af[i] = *reinterpret_cast<const i32x4*>(smem + aoff0 + (i << 11) + cb);
#pragma unroll
      for (int j = 0; j < 4; ++j)
        bfr[j] = *reinterpret_cast<const i32x4*>(smem + boff0 + (j << 11) + cb);
#pragma unroll
      for (int i = 0; i < 4; ++i)
#pragma unroll
        for (int j = 0; j < 4; ++j)
          acc[i][j] = __builtin_amdgcn_mfma_i32_16x16x64_i8(af[i], bfr[j], acc[i][j], 0, 0, 0);
    }
    __syncthreads();
  }

  const int r0 = bm + wm + ((lane >> 4) << 2);
  const int c0 = bn + wn + (lane & 15);
#pragma unroll
  for (int i = 0; i < 4; ++i)
#pragma unroll
    for (int j = 0; j < 4; ++j)
#pragma unroll
      for (int q = 0; q < 4; ++q) {
        const int r = r0 + (i << 4) + q;
        const int c = c0 + (j << 4);
        const size_t idx = (size_t)r * N + c;
        const float vg = (float)acc[i][j][q] * sA[r] * sB[c] + Bgate[c];
        const float g = 1.f / (1.f + __expf(-vg));
        Cf[idx] = Xf[idx] + g * __bfloat162float(PredBf[idx]);
      }
}

// ============================================================================
// kwta, wave-per-row (verified). Exact threshold via 16-step binary search on
// u16 bf16 keys (nonneg). Emits INT8 normalized row + scale.
// MODE 0: always write.  MODE 1: only when *vsumPtr >= EPS (else keep old).
// ============================================================================
template<int MODE>
__global__ void __launch_bounds__(256)
kwta_wave(const __hip_bfloat16* __restrict__ H, uint8_t* __restrict__ OUTQ,
          float* __restrict__ sA, const float* __restrict__ vsumPtr,
          const int* __restrict__ kptr)
{
  const int tid  = threadIdx.x;
  const int lane = tid & 63;
  const int w    = tid >> 6;
  const int row  = ((int)blockIdx.x << 2) + w;

  if constexpr (MODE == 1) {
    if (!(*vsumPtr >= 1e-10f)) return;
  }

  const uint4* h8 = (const uint4*)(H + (size_t)row * 4096);
  uint4 d[8];
#pragma unroll
  for (int i = 0; i < 8; ++i) d[i] = h8[(i << 6) + lane];

  const unsigned k = (unsigned)(*kptr);

  unsigned kmax = 0;
#pragma unroll
  for (int i = 0; i < 8; ++i) {
    const unsigned* p = (const unsigned*)&d[i];
#pragma unroll
    for (int c4 = 0; c4 < 4; ++c4) {
      kmax = max(kmax, p[c4] & 0xffffu);
      kmax = max(kmax, p[c4] >> 16);
    }
  }
#pragma unroll
  for (int off = 32; off > 0; off >>= 1) kmax = max(kmax, __shfl_xor(kmax, off));

  unsigned lo = 0, hi = 65536;
#pragma unroll 1
  for (int it = 0; it < 16; ++it) {
    const unsigned mid = (lo + hi) >> 1;
    unsigned c = 0;
#pragma unroll
    for (int i = 0; i < 8; ++i) {
      const unsigned* p = (const unsigned*)&d[i];
#pragma unroll
      for (int c4 = 0; c4 < 4; ++c4) {
        c += ((p[c4] & 0xffffu) >= mid) ? 1u : 0u;
        c += ((p[c4] >> 16) >= mid) ? 1u : 0u;
      }
    }
#pragma unroll
    for (int off = 32; off > 0; off >>= 1) c += __shfl_xor(c, off);
    if (c >= k) lo = mid; else hi = mid;
  }
  const unsigned threshKey = lo;

  float ss = 0.f;
#pragma unroll
  for (int i = 0; i < 8; ++i) {
    const unsigned* p = (const unsigned*)&d[i];
#pragma unroll
    for (int c4 = 0; c4 < 4; ++c4) {
#pragma unroll
      for (int hh = 0; hh < 2; ++hh) {
        const unsigned key = hh ? (p[c4] >> 16) : (p[c4] & 0xffffu);
        if (key >= threshKey) {
          const float v = __uint_as_float(key << 16);
          ss = fmaf(v, v, ss);
        }
      }
    }
  }
#pragma unroll
  for (int off = 32; off > 0; off >>= 1) ss += __shfl_xor(ss, off);
  const float inv = 1.f / fmaxf(sqrtf(ss), 1e-10f);

  const float vmaxf = __uint_as_float(kmax << 16);
  const float r127 = (kmax > 0) ? 127.f / vmaxf : 0.f;

  if (lane == 0) sA[row] = vmaxf * inv * (1.f / 127.f);

  uint2* o2 = (uint2*)(OUTQ + (size_t)row * 4096);
#pragma unroll
  for (int i = 0; i < 8; ++i) {
    const unsigned* p = (const unsigned*)&d[i];
    unsigned b[8];
#pragma unroll
    for (int c4 = 0; c4 < 4; ++c4) {
#pragma unroll
      for (int hh = 0; hh < 2; ++hh) {
        const unsigned key = hh ? (p[c4] >> 16) : (p[c4] & 0xffffu);
        unsigned q = 0;
        if (key >= threshKey && key > 0) {
          const float v = __uint_as_float(key << 16);
          q = (unsigned)__float2int_rn(v * r127) & 0xffu;
        }
        b[c4 * 2 + hh] = q;
      }
    }
    uint2 o;
    o.x = b[0] | (b[1] << 8) | (b[2] << 16) | (b[3] << 24);
    o.y = b[4] | (b[5] << 8) | (b[6] << 16) | (b[7] << 24);
    o2[(i << 6) + lane] = o;
  }
}

// ============================================================================
// Merged per-row quantization, one launch; also zero-inits vsum (block 0).
// ============================================================================
__global__ void __launch_bounds__(256)
quant_all(const float* __restrict__ X,  const float* __restrict__ Wd,
          const float* __restrict__ Wg, const float* __restrict__ Wc,
          const float* __restrict__ Wu,
          uint8_t* __restrict__ xq,  uint8_t* __restrict__ wdq,
          uint8_t* __restrict__ wgq, uint8_t* __restrict__ wcq,
          uint8_t* __restrict__ wuq,
          float* __restrict__ sx,  float* __restrict__ swd,
          float* __restrict__ swg, float* __restrict__ swc,
          float* __restrict__ swu, float* __restrict__ vsum)
{
  if (blockIdx.x == 0 && threadIdx.x == 0) *vsum = 0.f;

  const int wgl = ((int)blockIdx.x << 2) + (threadIdx.x >> 6);
  const int lane = threadIdx.x & 63;

  const float* W; uint8_t* q; float* s; int row; bool big;
  if      (wgl < 8192)  { W = X;  q = xq;  s = sx;  row = wgl;         big = false; }
  else if (wgl < 12288) { W = Wd; q = wdq; s = swd; row = wgl - 8192;  big = false; }
  else if (wgl < 13312) { W = Wg; q = wgq; s = swg; row = wgl - 12288; big = false; }
  else if (wgl < 17408) { W = Wc; q = wcq; s = swc; row = wgl - 13312; big = true; }
  else                  { W = Wu; q = wuq; s = swu; row = wgl - 17408; big = true; }

  if (!big) {
    const float4* src = (const float4*)(W + (size_t)row * 1024);
    float4 v[4];
    float am = 0.f;
#pragma unroll
    for (int i = 0; i < 4; ++i) {
      v[i] = src[(i << 6) + lane];
      am = fmaxf(am, fmaxf(fmaxf(fabsf(v[i].x), fabsf(v[i].y)),
                           fmaxf(fabsf(v[i].z), fabsf(v[i].w))));
    }
#pragma unroll
    for (int off = 32; off > 0; off >>= 1) am = fmaxf(am, __shfl_xor(am, off));
    const float rinv = (am > 0.f) ? 127.f / am : 0.f;
    uint4 o;
    unsigned* ob = (unsigned*)&o;
#pragma unroll
    for (int i = 0; i < 4; ++i) {
      const unsigned b0 = (unsigned)__float2int_rn(v[i].x * rinv) & 0xffu;
      const unsigned b1 = (unsigned)__float2int_rn(v[i].y * rinv) & 0xffu;
      const unsigned b2 = (unsigned)__float2int_rn(v[i].z * rinv) & 0xffu;
      const unsigned b3 = (unsigned)__float2int_rn(v[i].w * rinv) & 0xffu;
      ob[i] = b0 | (b1 << 8) | (b2 << 16) | (b3 << 24);
    }
    ((uint4*)(q + (size_t)row * 1024))[lane] = o;
    if (lane == 0) s[row] = am * (1.f / 127.f);
  } else {
    const float4* src = (const float4*)(W + (size_t)row * 4096);
    float4 v[16];
    float am = 0.f;
#pragma unroll
    for (int i = 0; i < 16; ++i) {
      v[i] = src[(i << 6) + lane];
      am = fmaxf(am, fmaxf(fmaxf(fabsf(v[i].x), fabsf(v[i].y)),
                           fmaxf(fabsf(v[i].z), fabsf(v[i].w))));
    }
#pragma unroll
    for (int off = 32; off > 0; off >>= 1) am = fmaxf(am, __shfl_xor(am, off));
    const float rinv = (am > 0.f) ? 127.f / am : 0.f;
    unsigned* qo = (unsigned*)(q + (size_t)row * 4096);
#pragma unroll
    for (int i = 0; i < 16; ++i) {
      const unsigned b0 = (unsigned)__float2int_rn(v[i].x * rinv) & 0xffu;
      const unsigned b1 = (unsigned)__float2int_rn(v[i].y * rinv) & 0xffu;
      const unsigned b2 = (unsigned)__float2int_rn(v[i].z * rinv) & 0xffu;
      const unsigned b3 = (unsigned)__float2int_rn(v[i].w * rinv) & 0xffu;
      qo[(i << 6) + lane] = b0 | (b1 << 8) | (b2 << 16) | (b3 << 24);
    }
    if (lane == 0) s[row] = am * (1.f / 127.f);
  }
}

__global__ void diag_kernel(float* out, float mb)
{
  if (threadIdx.x == 0 && blockIdx.x == 0) out[0] = -mb;
}

extern "C" void kernel_launch(void* const* d_in, const int* in_sizes, int n_in,
                              void* d_out, int out_size, void* d_ws, size_t ws_size,
                              hipStream_t stream)
{
  const float* x     = (const float*)d_in[0]; // (8192,1024)
  const float* Wdown = (const float*)d_in[1]; // (4096,1024)
  const float* Wup   = (const float*)d_in[2]; // (1024,4096)
  const float* Wgate = (const float*)d_in[3]; // (1024,1024)
  const float* bgate = (const float*)d_in[4]; // (1024,)
  const float* Wca3  = (const float*)d_in[5]; // (4096,4096)
  const int*   kptr  = (const int*)d_in[6];

  const size_t OFF_XQ   = 0;         //  8 MB i8 x
  const size_t OFF_WDQ  = 8388608;   //  4 MB i8 W_down
  const size_t OFF_WGQ  = 12582912;  //  1 MB i8 W_gate
  const size_t OFF_WCQ  = 13631488;  // 16 MB i8 W_ca3
  const size_t OFF_WUQ  = 30408704;  //  4 MB i8 W_up
  const size_t OFF_SX   = 34603008;  // 32 KB
  const size_t OFF_SWD  = 34635776;  // 16 KB
  const size_t OFF_SWG  = 34652160;  //  4 KB
  const size_t OFF_SWC  = 34656256;  // 16 KB
  const size_t OFF_SWU  = 34672640;  //  4 KB
  const size_t OFF_SA   = 34676736;  // 32 KB
  const size_t OFF_VSUM = 34709504;  //  4 KB pad
  const size_t OFF_SPQ  = 34713600;  // 32 MB i8 sparse/successor
  const size_t OFF_H    = 68268032;  // 64 MB bf16 h1/h2; pred (16 MB bf16) aliases
  const size_t NEED     = 135376896;

  if (ws_size < NEED) {
    diag_kernel<<<1, 64, 0, stream>>>((float*)d_out, (float)(ws_size >> 20));
    return;
  }

  char* ws = (char*)d_ws;
  uint8_t*        xq   = (uint8_t*)       (ws + OFF_XQ);
  uint8_t*        wdq  = (uint8_t*)       (ws + OFF_WDQ);
  uint8_t*        wgq  = (uint8_t*)       (ws + OFF_WGQ);
  uint8_t*        wcq  = (uint8_t*)       (ws + OFF_WCQ);
  uint8_t*        wuq  = (uint8_t*)       (ws + OFF_WUQ);
  float*          sx   = (float*)         (ws + OFF_SX);
  float*          swd  = (float*)         (ws + OFF_SWD);
  float*          swg  = (float*)         (ws + OFF_SWG);
  float*          swc  = (float*)         (ws + OFF_SWC);
  float*          swu  = (float*)         (ws + OFF_SWU);
  float*          sA   = (float*)         (ws + OFF_SA);
  float*          vsum = (float*)         (ws + OFF_VSUM);
  uint8_t*        spq  = (uint8_t*)       (ws + OFF_SPQ);
  __hip_bfloat16* h    = (__hip_bfloat16*)(ws + OFF_H);
  __hip_bfloat16* pred = (__hip_bfloat16*)(ws + OFF_H);   // aliases h (dead by then)

  // quantize all inputs/weights to i8 with per-row scales; zero vsum
  quant_all<<<4608, 256, 0, stream>>>(x, Wdown, Wgate, Wca3, Wup,
                                      xq, wdq, wgq, wcq, wuq,
                                      sx, swd, swg, swc, swu, vsum);

  // h1 = relu(sx*swd * (xq @ wdq^T)) -> bf16   [i8 8-phase 256^2, supertile]
  gemm_i8_8ph<0><<<(MROWS >> 8) * (DN >> 8), 512, 131072, stream>>>(
      xq, wdq, h, MROWS, DN, DD, nullptr, sx, swd);
  // sparse = kwta(h1)/norm -> i8 + scale
  kwta_wave<0><<<MROWS / 4, 256, 0, stream>>>(h, spq, sA, nullptr, kptr);
  // h2 = relu(sA*swc * (spq @ wcq^T)) -> bf16, sum -> vsum   [i8 8-phase]
  gemm_i8_8ph<1><<<(MROWS >> 8) * (DN >> 8), 512, 131072, stream>>>(
      spq, wcq, h, MROWS, DN, DN, vsum, sA, swc);
  // successor = valid ? kwta(h2)/norm : sparse (i8 + scale, in-place)
  kwta_wave<1><<<MROWS / 4, 256, 0, stream>>>(h, spq, sA, vsum, kptr);
  // pred = (spq @ wuq^T) deq -> bf16   [i8 128^2 + swizzle, grid 512]
  gemm_i8_128<<<(MROWS >> 7) * (DD >> 7), 256, 0, stream>>>(
      spq, wuq, pred, MROWS, DD, DN, sA, swu);
  // out = x + sigmoid(deq(xq @ wgq^T) + bgate) * pred   [i8 128^2]
  gemm_gate_i8<<<(MROWS >> 7) * (DD >> 7), 256, 0, stream>>>(
      xq, wgq, (float*)d_out, MROWS, DD, DD, sx, swg, x, pred, bgate);
}